// Round 1
// 80.090 us; speedup vs baseline: 1.0320x; 1.0320x over previous
//
#include <hip/hip_runtime.h>
#include <math.h>

#define N_TOTAL 8192
#define BATCH   4096
#define DIMS    64
#define P1_BLOCKS 128    // 128 blocks x 8 waves = 1024 waves -> 2 group-iters/wave
#define SEG     8
#define P2_BLOCKS 1088   // live-only: sum_{bc=0}^{127} (bc/8 + 1)

// ws layout (bytes):
//   0       double sqpart[128]       (per-block sum of sq norms)
//   1024    double colpart[128*64]   (per-block col sums, block-major) -> 66560
//   66560   float  sq[8192]
//   99328   short  Xh[8192*64]       (bf16, row-major)
//
// R19: scale_kernel ELIMINATED (3 -> 2 dispatches). pass1 shrunk to 128
// blocks so colpart is 64 KB; every pass2 block redundantly reduces
// colpart/sqpart itself (16 coalesced f64 loads/thread, overlapped with
// B-tile staging) and computes cs deterministically -- bitwise identical
// across blocks, no atomics, no init, no fence. out[0] zeroed by pass1
// thread 0; kernel-boundary ordering covers pass2's atomics.
//
// No memset: every ws slot is written before it is read. d_out zeroed by
// pass1 (kernel-boundary ordering), pass2 accumulates into it with
// pre-scaled float atomicAdds (no fence, no counter -- R17 lesson: the
// fence+counter protocol costs +15us; bare commutative atomics don't).
//
// bf16-only GEMM (no hi/lo compensation): errL2 std ~0.05 -> grand-sum error
// ~5e-7 vs threshold 3.16e-5 (60x margin). Norms/bandwidth stay exact.
// 1/BATCH^2 = 2^-24: scaling each partial is EXACT in fp32; atomic-order
// accumulation error ~2.5e-7.
// R14 lesson: never __threadfence() on the all-threads path (L2 storm).

#if defined(__has_builtin)
#if __has_builtin(__builtin_amdgcn_exp2f)
#define EXP2F(x) __builtin_amdgcn_exp2f(x)
#endif
#endif
#ifndef EXP2F
#define EXP2F(x) exp2f(x)
#endif

typedef __attribute__((ext_vector_type(8))) short bf16x8;
typedef __attribute__((ext_vector_type(4))) float f32x4;
typedef __attribute__((ext_vector_type(2))) float f32x2;
typedef __attribute__((ext_vector_type(4))) short s16x4;

__device__ inline short f2bf_rn(float x) {
    unsigned u = __float_as_uint(x);
    unsigned r = (u + 0x7fffu + ((u >> 16) & 1u)) >> 16;
    return (short)r;
}

// pass1: fp32 -> bf16 (once), row sq-norms (exact fp32), per-block col/sq
// partials stored to memory. 128 blocks x 8 waves -> 2 group-iters per wave.
__global__ __launch_bounds__(512) void pass1_kernel(const float* __restrict__ src,
                                                    const float* __restrict__ tgt,
                                                    double* __restrict__ sqpart,
                                                    double* __restrict__ colpart,
                                                    float* __restrict__ sqbuf,
                                                    short* __restrict__ Xh,
                                                    float* __restrict__ out) {
    __shared__ double cred[8][64];
    __shared__ double sred[8];
    const int lane = threadIdx.x & 63;
    const int wv = threadIdx.x >> 6;
    const int sub = lane >> 4;
    const int k4 = (lane & 15) << 2;
    const int gw = blockIdx.x * 8 + wv;
    const int numWaves = P1_BLOCKS * 8;

    if (blockIdx.x == 0 && threadIdx.x == 0) out[0] = 0.f;   // poisoned 0xAA by harness

    double colacc[4] = {0.0, 0.0, 0.0, 0.0};
    double sqacc = 0.0;

    for (int g = gw; g < N_TOTAL / 4; g += numWaves) {
        int r = g * 4 + sub;
        const float* row = (r < BATCH) ? (src + (size_t)r * DIMS)
                                       : (tgt + (size_t)(r - BATCH) * DIMS);
        float4 v = *(const float4*)(row + k4);
        float xs[4] = {v.x, v.y, v.z, v.w};
        s16x4 h;
        float ssum = 0.f;
        #pragma unroll
        for (int i = 0; i < 4; ++i) {
            h[i] = f2bf_rn(xs[i]);
            colacc[i] += (double)xs[i];
            ssum = fmaf(xs[i], xs[i], ssum);
        }
        *(s16x4*)(Xh + (size_t)r * DIMS + k4) = h;
        ssum += __shfl_xor(ssum, 1, 64);
        ssum += __shfl_xor(ssum, 2, 64);
        ssum += __shfl_xor(ssum, 4, 64);
        ssum += __shfl_xor(ssum, 8, 64);
        if ((lane & 15) == 0) { sqbuf[r] = ssum; sqacc += (double)ssum; }
    }
    #pragma unroll
    for (int i = 0; i < 4; ++i) {
        colacc[i] += __shfl_xor(colacc[i], 16, 64);
        colacc[i] += __shfl_xor(colacc[i], 32, 64);
    }
    sqacc += __shfl_xor(sqacc, 16, 64);
    sqacc += __shfl_xor(sqacc, 32, 64);
    if (lane < 16) {
        #pragma unroll
        for (int i = 0; i < 4; ++i) cred[wv][lane * 4 + i] = colacc[i];
    }
    if (lane == 0) sred[wv] = sqacc;
    __syncthreads();
    if (wv == 0) {
        double c = ((cred[0][lane] + cred[1][lane]) + (cred[2][lane] + cred[3][lane]))
                 + ((cred[4][lane] + cred[5][lane]) + (cred[6][lane] + cred[7][lane]));
        colpart[(size_t)blockIdx.x * 64 + lane] = c;     // coalesced store
        if (lane == 0)
            sqpart[blockIdx.x] = ((sred[0] + sred[1]) + (sred[2] + sred[3]))
                               + ((sred[4] + sred[5]) + (sred[6] + sred[7]));
    }
}

// pass2: frozen best body (R18) + per-block redundant bandwidth reduce (R19).
// Flat live-only grid of 1088 blocks. 512-thread blocks = 8 waves share one
// LDS B-tile; per tile-iter: 2 global A-loads, 8 LDS b128, 8 MFMA, packed-fp32
// exp epilogue. Block result is scaled by exact 2^-24 and atomically added.
__global__ __launch_bounds__(512) void pass2_kernel(const short* __restrict__ Xh,
                                                    const float* __restrict__ sqbuf,
                                                    const double* __restrict__ sqpart,
                                                    const double* __restrict__ colpart,
                                                    float* __restrict__ out) {
    // decode flat id: band b (bc=8b+q) has 8 bc x (b+1) segments
    const int f = blockIdx.x;
    int b = 0;
    while (4 * (b + 1) * (b + 2) <= f) ++b;          // <=15 steps
    const int rem = f - 4 * b * (b + 1);
    const int q = rem / (b + 1);
    const int bc = 8 * b + q;
    const int seg = rem - q * (b + 1);
    const int r0 = seg * SEG;
    const int r1 = (bc < r0 + SEG - 1) ? bc : r0 + SEG - 1;

    __shared__ __align__(16) short Bh[64][72];
    __shared__ double dcred[8][64];
    __shared__ double s_sq[128];
    __shared__ float s_wred[8];
    __shared__ float s_cs;

    const int t = threadIdx.x;
    const int lane = t & 63, w = t >> 6;
    const int strip = w & 3, ts = w >> 2;
    const int quad = lane >> 4, lrow = lane & 15;

    // stage B column-tile into LDS: 512 threads, one shot
    {
        int row = t >> 3;            // 0..63
        int c8 = (t & 7) << 3;       // short offset 0..56
        size_t gsrc = (size_t)(bc * 64 + row) * DIMS + c8;
        *(s16x4*)&Bh[row][c8]     = *(const s16x4*)(Xh + gsrc);
        *(s16x4*)&Bh[row][c8 + 4] = *(const s16x4*)(Xh + gsrc + 4);
    }

    // redundant bandwidth reduce (overlaps with B staging; all L2/L3-hot)
    {
        const int c = lane;          // t = w*64 + lane -> coalesced per wave
        double colacc = 0.0;
        #pragma unroll
        for (int b2 = 0; b2 < P1_BLOCKS / 8; ++b2)
            colacc += colpart[(size_t)(w + b2 * 8) * 64 + c];
        dcred[w][c] = colacc;
    }
    if (t < 128) s_sq[t] = sqpart[t];

    // raw B-row sq norms (scaled after cs is known)
    float sraw[4];
    #pragma unroll
    for (int j = 0; j < 4; ++j)
        sraw[j] = sqbuf[bc * 64 + j * 16 + lrow];

    __syncthreads();

    if (w == 0) {
        double colsum = ((dcred[0][lane] + dcred[1][lane]) + (dcred[2][lane] + dcred[3][lane]))
                      + ((dcred[4][lane] + dcred[5][lane]) + (dcred[6][lane] + dcred[7][lane]));
        double vv = colsum * colsum;
        double sacc = s_sq[lane] + s_sq[lane + 64];
        #pragma unroll
        for (int off = 32; off > 0; off >>= 1) {
            vv += __shfl_xor(vv, off, 64);
            sacc += __shfl_xor(sacc, off, 64);
        }
        if (lane == 0) {
            const double n = (double)N_TOTAL;
            double bw0 = (2.0 * n * sacc - 2.0 * vv) / (n * n - n) * 0.25;
            s_cs = (float)(-1.0 / (bw0 * 0.6931471805599453 * 16.0));
        }
    }
    __syncthreads();

    const float cs = s_cs;
    const float c2 = -2.f * cs;
    const f32x2 c2v = (f32x2){c2, c2};
    f32x2 sbj[4];
    #pragma unroll
    for (int j = 0; j < 4; ++j) {
        float s = sraw[j] * cs;
        sbj[j] = (f32x2){s, s};
    }

    const size_t aoff = (size_t)(strip * 16 + lrow) * DIMS + quad * 8;

    float facc = 0.f;

    for (int r = r0 + ts; r <= r1; r += 2) {
        const size_t abase = (size_t)r * 64 * DIMS + aoff;
        bf16x8 ah0 = *(const bf16x8*)(Xh + abase);
        bf16x8 ah1 = *(const bf16x8*)(Xh + abase + 32);
        float4 csa = *(const float4*)(sqbuf + r * 64 + strip * 16 + quad * 4);

        f32x4 acc[4];
        #pragma unroll
        for (int j = 0; j < 4; ++j) acc[j] = (f32x4){0.f, 0.f, 0.f, 0.f};
        #pragma unroll
        for (int j = 0; j < 4; ++j) {
            const int brow = j * 16 + lrow;
            const int bcol = quad * 8;
            bf16x8 bh0 = *(const bf16x8*)&Bh[brow][bcol];
            bf16x8 bh1 = *(const bf16x8*)&Bh[brow][bcol + 32];
            acc[j] = __builtin_amdgcn_mfma_f32_16x16x32_bf16(ah0, bh0, acc[j], 0, 0, 0);
            acc[j] = __builtin_amdgcn_mfma_f32_16x16x32_bf16(ah1, bh1, acc[j], 0, 0, 0);
        }

        const f32x2 sa01 = (f32x2){csa.x * cs, csa.y * cs};
        const f32x2 sa23 = (f32x2){csa.z * cs, csa.w * cs};
        f32x2 lsum2 = (f32x2){0.f, 0.f};
        #pragma unroll
        for (int j = 0; j < 4; ++j) {
            // t0 = -L2/(16*bw0*ln2) on element pairs (packed fp32)
            f32x2 a01 = (f32x2){acc[j][0], acc[j][1]};
            f32x2 a23 = (f32x2){acc[j][2], acc[j][3]};
            f32x2 t01 = a01 * c2v + (sa01 + sbj[j]);
            f32x2 t23 = a23 * c2v + (sa23 + sbj[j]);
            // 1 exp2 + 4 packed squarings = all 5 bandwidth kernels
            f32x2 e4a = (f32x2){EXP2F(t01[0]), EXP2F(t01[1])};
            f32x2 e4b = (f32x2){EXP2F(t23[0]), EXP2F(t23[1])};
            f32x2 e3a = e4a * e4a, e3b = e4b * e4b;
            f32x2 e2a = e3a * e3a, e2b = e3b * e3b;
            f32x2 e1a = e2a * e2a, e1b = e2b * e2b;
            f32x2 e0a = e1a * e1a, e0b = e1b * e1b;
            lsum2 += ((e0a + e1a) + (e2a + e3a)) + e4a;
            lsum2 += ((e0b + e1b) + (e2b + e3b)) + e4b;
        }
        float lsum = lsum2[0] + lsum2[1];
        float sgn = ((r < 64) == (bc < 64)) ? 1.f : -1.f;
        float wt  = (r == bc) ? 1.f : 2.f;
        facc = fmaf(lsum, sgn * wt, facc);
    }

    #pragma unroll
    for (int off = 32; off > 0; off >>= 1) facc += __shfl_xor(facc, off, 64);
    if (lane == 0) s_wred[w] = facc;
    __syncthreads();
    if (t == 0) {
        float bsum = ((s_wred[0] + s_wred[1]) + (s_wred[2] + s_wred[3]))
                   + ((s_wred[4] + s_wred[5]) + (s_wred[6] + s_wred[7]));
        // 1/BATCH^2 = 2^-24: exact fp32 scaling; bare atomic, no fence
        atomicAdd(out, bsum * 5.9604644775390625e-08f);
    }
}

extern "C" void kernel_launch(void* const* d_in, const int* in_sizes, int n_in,
                              void* d_out, int out_size, void* d_ws, size_t ws_size,
                              hipStream_t stream) {
    const float* src = (const float*)d_in[0];
    const float* tgt = (const float*)d_in[1];
    char* ws = (char*)d_ws;
    double* sqpart  = (double*)ws;
    double* colpart = (double*)(ws + 1024);
    float*  sqbuf   = (float*)(ws + 66560);
    short*  Xh      = (short*)(ws + 99328);

    // no memset: every ws slot is written before it is read

    pass1_kernel<<<P1_BLOCKS, 512, 0, stream>>>(src, tgt, sqpart, colpart,
                                                sqbuf, Xh, (float*)d_out);
    pass2_kernel<<<P2_BLOCKS, 512, 0, stream>>>(Xh, sqbuf, sqpart, colpart,
                                                (float*)d_out);
}

// Round 2
// 79.948 us; speedup vs baseline: 1.0339x; 1.0018x over previous
//
#include <hip/hip_runtime.h>
#include <math.h>

#define N_TOTAL 8192
#define BATCH   4096
#define DIMS    64
#define P1_BLOCKS 128    // 128 blocks x 8 waves = 1024 waves -> 2 group-iters/wave
#define SEG     16
#define P2_BLOCKS 576    // live-only: sum_{bc=0}^{127} (bc/16 + 1) = 16*(1+..+8)

// ws layout (bytes):
//   0       double sqpart[128]       (per-block sum of sq norms)
//   1024    double colpart[128*64]   (per-block col sums, block-major) -> 66560
//   66560   float  sq[8192]
//   99328   short  Xh[8192*64]       (bf16, row-major)
//
// R20: pass2 overhead amortization. SEG 8->16 (1088 -> 576 blocks) halves
// per-block setup cost per unit of compute (avg 3.8 -> 7.2 iters/wave).
// cs is now computed REDUNDANTLY BY EVERY WAVE (identical op order =>
// bitwise identical result) -- kills the wave0 serialization + the second
// __syncthreads. Heavy blocks dispatch first (f = 575 - blockIdx.x) so the
// scheduling tail is packed with 1-iter blocks. B-stage is one b128 store
// per thread (uniform 8 dwords/bank, the wave64 minimum).
//
// R19: scale_kernel eliminated (2 dispatches). Every pass2 block reduces
// colpart/sqpart itself; no atomics, no init, no fence. out[0] zeroed by
// pass1 thread 0; kernel-boundary ordering covers pass2's atomics.
//
// No memset: every ws slot is written before it is read. pass2 accumulates
// into d_out with pre-scaled float atomicAdds (no fence, no counter -- R17
// lesson: fence+counter costs +15us; bare commutative atomics don't).
//
// bf16-only GEMM (no hi/lo compensation): errL2 std ~0.05 -> grand-sum error
// ~5e-7 vs threshold 3.16e-5 (60x margin). Norms/bandwidth stay exact.
// 1/BATCH^2 = 2^-24: scaling each partial is EXACT in fp32; atomic-order
// accumulation error ~2.5e-7.
// R14 lesson: never __threadfence() on the all-threads path (L2 storm).
// Bh[64][72] pad: b128 reads land 8 dwords on every bank (uniform minimum,
// NOT a conflict) -- do not re-pad.

#if defined(__has_builtin)
#if __has_builtin(__builtin_amdgcn_exp2f)
#define EXP2F(x) __builtin_amdgcn_exp2f(x)
#endif
#endif
#ifndef EXP2F
#define EXP2F(x) exp2f(x)
#endif

typedef __attribute__((ext_vector_type(8))) short bf16x8;
typedef __attribute__((ext_vector_type(4))) float f32x4;
typedef __attribute__((ext_vector_type(2))) float f32x2;
typedef __attribute__((ext_vector_type(4))) short s16x4;
typedef __attribute__((ext_vector_type(8))) short s16x8;

__device__ inline short f2bf_rn(float x) {
    unsigned u = __float_as_uint(x);
    unsigned r = (u + 0x7fffu + ((u >> 16) & 1u)) >> 16;
    return (short)r;
}

// pass1: fp32 -> bf16 (once), row sq-norms (exact fp32), per-block col/sq
// partials stored to memory. 128 blocks x 8 waves -> 2 group-iters per wave.
__global__ __launch_bounds__(512) void pass1_kernel(const float* __restrict__ src,
                                                    const float* __restrict__ tgt,
                                                    double* __restrict__ sqpart,
                                                    double* __restrict__ colpart,
                                                    float* __restrict__ sqbuf,
                                                    short* __restrict__ Xh,
                                                    float* __restrict__ out) {
    __shared__ double cred[8][64];
    __shared__ double sred[8];
    const int lane = threadIdx.x & 63;
    const int wv = threadIdx.x >> 6;
    const int sub = lane >> 4;
    const int k4 = (lane & 15) << 2;
    const int gw = blockIdx.x * 8 + wv;
    const int numWaves = P1_BLOCKS * 8;

    if (blockIdx.x == 0 && threadIdx.x == 0) out[0] = 0.f;   // poisoned 0xAA by harness

    double colacc[4] = {0.0, 0.0, 0.0, 0.0};
    double sqacc = 0.0;

    for (int g = gw; g < N_TOTAL / 4; g += numWaves) {
        int r = g * 4 + sub;
        const float* row = (r < BATCH) ? (src + (size_t)r * DIMS)
                                       : (tgt + (size_t)(r - BATCH) * DIMS);
        float4 v = *(const float4*)(row + k4);
        float xs[4] = {v.x, v.y, v.z, v.w};
        s16x4 h;
        float ssum = 0.f;
        #pragma unroll
        for (int i = 0; i < 4; ++i) {
            h[i] = f2bf_rn(xs[i]);
            colacc[i] += (double)xs[i];
            ssum = fmaf(xs[i], xs[i], ssum);
        }
        *(s16x4*)(Xh + (size_t)r * DIMS + k4) = h;
        ssum += __shfl_xor(ssum, 1, 64);
        ssum += __shfl_xor(ssum, 2, 64);
        ssum += __shfl_xor(ssum, 4, 64);
        ssum += __shfl_xor(ssum, 8, 64);
        if ((lane & 15) == 0) { sqbuf[r] = ssum; sqacc += (double)ssum; }
    }
    #pragma unroll
    for (int i = 0; i < 4; ++i) {
        colacc[i] += __shfl_xor(colacc[i], 16, 64);
        colacc[i] += __shfl_xor(colacc[i], 32, 64);
    }
    sqacc += __shfl_xor(sqacc, 16, 64);
    sqacc += __shfl_xor(sqacc, 32, 64);
    if (lane < 16) {
        #pragma unroll
        for (int i = 0; i < 4; ++i) cred[wv][lane * 4 + i] = colacc[i];
    }
    if (lane == 0) sred[wv] = sqacc;
    __syncthreads();
    if (wv == 0) {
        double c = ((cred[0][lane] + cred[1][lane]) + (cred[2][lane] + cred[3][lane]))
                 + ((cred[4][lane] + cred[5][lane]) + (cred[6][lane] + cred[7][lane]));
        colpart[(size_t)blockIdx.x * 64 + lane] = c;     // coalesced store
        if (lane == 0)
            sqpart[blockIdx.x] = ((sred[0] + sred[1]) + (sred[2] + sred[3]))
                               + ((sred[4] + sred[5]) + (sred[6] + sred[7]));
    }
}

// pass2: frozen best compute body (R18) + SEG=16 amortization (R20).
// Flat live-only grid of 576 blocks, heavy-first. 512-thread blocks = 8
// waves share one LDS B-tile; per tile-iter: 2 global A-loads, 8 LDS b128,
// 8 MFMA, packed-fp32 exp epilogue. Block result is scaled by exact 2^-24
// and atomically added to out.
__global__ __launch_bounds__(512) void pass2_kernel(const short* __restrict__ Xh,
                                                    const float* __restrict__ sqbuf,
                                                    const double* __restrict__ sqpart,
                                                    const double* __restrict__ colpart,
                                                    float* __restrict__ out) {
    // heavy-first: reverse flat id, then decode. band B (bc=16B+q) has
    // 16 bc x (B+1) segments; blocks before band B = 8*B*(B+1).
    const int f = (P2_BLOCKS - 1) - blockIdx.x;
    int B = 0;
    while (8 * (B + 1) * (B + 2) <= f) ++B;          // <=7 steps
    const int rem = f - 8 * B * (B + 1);
    const int q = rem / (B + 1);
    const int bc = 16 * B + q;
    const int seg = rem - q * (B + 1);
    const int r0 = seg * SEG;
    const int r1 = (bc < r0 + SEG - 1) ? bc : r0 + SEG - 1;

    __shared__ __align__(16) short Bh[64][72];
    __shared__ double dcred[8][64];
    __shared__ double s_sq[128];
    __shared__ float s_wred[8];

    const int t = threadIdx.x;
    const int lane = t & 63, w = t >> 6;
    const int strip = w & 3, ts = w >> 2;
    const int quad = lane >> 4, lrow = lane & 15;

    // stage B column-tile into LDS: 512 threads, one b128 store each
    {
        int row = t >> 3;            // 0..63
        int c8 = (t & 7) << 3;       // short offset 0..56
        size_t gsrc = (size_t)(bc * 64 + row) * DIMS + c8;
        *(s16x8*)&Bh[row][c8] = *(const s16x8*)(Xh + gsrc);
    }

    // distributed bandwidth partial reduce (overlaps B staging; L2/L3-hot)
    {
        const int c = lane;          // t = w*64 + lane -> coalesced per wave
        double colacc = 0.0;
        #pragma unroll
        for (int b2 = 0; b2 < P1_BLOCKS / 8; ++b2)
            colacc += colpart[(size_t)(w + b2 * 8) * 64 + c];
        dcred[w][c] = colacc;
    }
    if (t < 128) s_sq[t] = sqpart[t];

    // raw B-row sq norms (scaled once cs is known)
    float sraw[4];
    #pragma unroll
    for (int j = 0; j < 4; ++j)
        sraw[j] = sqbuf[bc * 64 + j * 16 + lrow];

    __syncthreads();

    // every wave computes cs redundantly: identical op order everywhere =>
    // bitwise-identical scalar; no second barrier, no wave0 serialization.
    float cs;
    {
        double colsum = ((dcred[0][lane] + dcred[1][lane]) + (dcred[2][lane] + dcred[3][lane]))
                      + ((dcred[4][lane] + dcred[5][lane]) + (dcred[6][lane] + dcred[7][lane]));
        double vv = colsum * colsum;
        double sacc = s_sq[lane] + s_sq[lane + 64];
        #pragma unroll
        for (int off = 32; off > 0; off >>= 1) {
            vv += __shfl_xor(vv, off, 64);
            sacc += __shfl_xor(sacc, off, 64);
        }
        const double n = (double)N_TOTAL;
        double bw0 = (2.0 * n * sacc - 2.0 * vv) / (n * n - n) * 0.25;
        cs = (float)(-1.0 / (bw0 * 0.6931471805599453 * 16.0));
    }

    const float c2 = -2.f * cs;
    const f32x2 c2v = (f32x2){c2, c2};
    f32x2 sbj[4];
    #pragma unroll
    for (int j = 0; j < 4; ++j) {
        float s = sraw[j] * cs;
        sbj[j] = (f32x2){s, s};
    }

    const size_t aoff = (size_t)(strip * 16 + lrow) * DIMS + quad * 8;

    float facc = 0.f;

    for (int r = r0 + ts; r <= r1; r += 2) {
        const size_t abase = (size_t)r * 64 * DIMS + aoff;
        bf16x8 ah0 = *(const bf16x8*)(Xh + abase);
        bf16x8 ah1 = *(const bf16x8*)(Xh + abase + 32);
        float4 csa = *(const float4*)(sqbuf + r * 64 + strip * 16 + quad * 4);

        f32x4 acc[4];
        #pragma unroll
        for (int j = 0; j < 4; ++j) acc[j] = (f32x4){0.f, 0.f, 0.f, 0.f};
        #pragma unroll
        for (int j = 0; j < 4; ++j) {
            const int brow = j * 16 + lrow;
            const int bcol = quad * 8;
            bf16x8 bh0 = *(const bf16x8*)&Bh[brow][bcol];
            bf16x8 bh1 = *(const bf16x8*)&Bh[brow][bcol + 32];
            acc[j] = __builtin_amdgcn_mfma_f32_16x16x32_bf16(ah0, bh0, acc[j], 0, 0, 0);
            acc[j] = __builtin_amdgcn_mfma_f32_16x16x32_bf16(ah1, bh1, acc[j], 0, 0, 0);
        }

        const f32x2 sa01 = (f32x2){csa.x * cs, csa.y * cs};
        const f32x2 sa23 = (f32x2){csa.z * cs, csa.w * cs};
        f32x2 lsum2 = (f32x2){0.f, 0.f};
        #pragma unroll
        for (int j = 0; j < 4; ++j) {
            // t0 = -L2/(16*bw0*ln2) on element pairs (packed fp32)
            f32x2 a01 = (f32x2){acc[j][0], acc[j][1]};
            f32x2 a23 = (f32x2){acc[j][2], acc[j][3]};
            f32x2 t01 = a01 * c2v + (sa01 + sbj[j]);
            f32x2 t23 = a23 * c2v + (sa23 + sbj[j]);
            // 1 exp2 + 4 packed squarings = all 5 bandwidth kernels
            f32x2 e4a = (f32x2){EXP2F(t01[0]), EXP2F(t01[1])};
            f32x2 e4b = (f32x2){EXP2F(t23[0]), EXP2F(t23[1])};
            f32x2 e3a = e4a * e4a, e3b = e4b * e4b;
            f32x2 e2a = e3a * e3a, e2b = e3b * e3b;
            f32x2 e1a = e2a * e2a, e1b = e2b * e2b;
            f32x2 e0a = e1a * e1a, e0b = e1b * e1b;
            lsum2 += ((e0a + e1a) + (e2a + e3a)) + e4a;
            lsum2 += ((e0b + e1b) + (e2b + e3b)) + e4b;
        }
        float lsum = lsum2[0] + lsum2[1];
        float sgn = ((r < 64) == (bc < 64)) ? 1.f : -1.f;
        float wt  = (r == bc) ? 1.f : 2.f;
        facc = fmaf(lsum, sgn * wt, facc);
    }

    #pragma unroll
    for (int off = 32; off > 0; off >>= 1) facc += __shfl_xor(facc, off, 64);
    if (lane == 0) s_wred[w] = facc;
    __syncthreads();
    if (t == 0) {
        float bsum = ((s_wred[0] + s_wred[1]) + (s_wred[2] + s_wred[3]))
                   + ((s_wred[4] + s_wred[5]) + (s_wred[6] + s_wred[7]));
        // 1/BATCH^2 = 2^-24: exact fp32 scaling; bare atomic, no fence
        atomicAdd(out, bsum * 5.9604644775390625e-08f);
    }
}

extern "C" void kernel_launch(void* const* d_in, const int* in_sizes, int n_in,
                              void* d_out, int out_size, void* d_ws, size_t ws_size,
                              hipStream_t stream) {
    const float* src = (const float*)d_in[0];
    const float* tgt = (const float*)d_in[1];
    char* ws = (char*)d_ws;
    double* sqpart  = (double*)ws;
    double* colpart = (double*)(ws + 1024);
    float*  sqbuf   = (float*)(ws + 66560);
    short*  Xh      = (short*)(ws + 99328);

    // no memset: every ws slot is written before it is read

    pass1_kernel<<<P1_BLOCKS, 512, 0, stream>>>(src, tgt, sqpart, colpart,
                                                sqbuf, Xh, (float*)d_out);
    pass2_kernel<<<P2_BLOCKS, 512, 0, stream>>>(Xh, sqbuf, sqpart, colpart,
                                                (float*)d_out);
}